// Round 12
// baseline (269.249 us; speedup 1.0000x reference)
//
#include <hip/hip_runtime.h>
#include <hip/hip_bf16.h>
#include <stdint.h>

// Problem constants
#define B_   512
#define T_   87
#define C_   512
#define H_   8
#define D_   64
#define BT_  44544        // B_*T_
#define BH_  4096         // B_*H_

typedef __attribute__((ext_vector_type(4))) float f32x4;
typedef __attribute__((ext_vector_type(8))) __bf16 bf16x8;
typedef __attribute__((ext_vector_type(4))) unsigned short u16x4;
typedef __attribute__((ext_vector_type(8))) unsigned short u16x8;

__device__ __forceinline__ int mod29(int x) {
  return x < 29 ? x : (x < 58 ? x - 29 : x - 58);
}

__device__ __forceinline__ bf16x8 cvt8(f32x4 a, f32x4 b) {
  u16x8 u;
  u[0] = __builtin_bit_cast(unsigned short, __float2bfloat16(a.x));
  u[1] = __builtin_bit_cast(unsigned short, __float2bfloat16(a.y));
  u[2] = __builtin_bit_cast(unsigned short, __float2bfloat16(a.z));
  u[3] = __builtin_bit_cast(unsigned short, __float2bfloat16(a.w));
  u[4] = __builtin_bit_cast(unsigned short, __float2bfloat16(b.x));
  u[5] = __builtin_bit_cast(unsigned short, __float2bfloat16(b.y));
  u[6] = __builtin_bit_cast(unsigned short, __float2bfloat16(b.z));
  u[7] = __builtin_bit_cast(unsigned short, __float2bfloat16(b.w));
  return __builtin_bit_cast(bf16x8, u);
}

// ---------------- W convert ----------------
__global__ void convert_w_kernel(const float* __restrict__ Wq, const float* __restrict__ Wk,
                                 const float* __restrict__ Wv, const float* __restrict__ Wp,
                                 const float* __restrict__ bq, const float* __restrict__ bk,
                                 const float* __restrict__ bv,
                                 __hip_bfloat16* __restrict__ wqkv,
                                 __hip_bfloat16* __restrict__ wp,
                                 float* __restrict__ biasc) {
  const int NW = 262144;                 // 512*512
  const int total = 3 * NW + NW + 1536;
  int stride = gridDim.x * blockDim.x;
  for (int i = blockIdx.x * blockDim.x + threadIdx.x; i < total; i += stride) {
    if (i < 3 * NW) {
      float v = (i < NW) ? Wq[i] : (i < 2 * NW ? Wk[i - NW] : Wv[i - 2 * NW]);
      wqkv[i] = __float2bfloat16(v);
    } else if (i < 4 * NW) {
      wp[i - 3 * NW] = __float2bfloat16(Wp[i - 3 * NW]);
    } else {
      int j = i - 4 * NW;
      biasc[j] = (j < 512) ? bq[j] : (j < 1024 ? bk[j - 512] : bv[j - 1024]);
    }
  }
}

// ---------------- shared compute tile (R7 core) ----------------
template<int FM, int FN>
__device__ __forceinline__ void compute_tile(const char* Ab, const char* Bb,
                                             int wbM, int wbN, int r16, int r4,
                                             f32x4 acc[FM][FN]) {
  const int cxor = (r16 & 7) << 4;
  bf16x8 bf[FN][2];
#pragma unroll
  for (int fn = 0; fn < FN; ++fn) {
    int row = wbN + fn * 16 + r16;
#pragma unroll
    for (int kk = 0; kk < 2; ++kk)
      bf[fn][kk] = *(const bf16x8*)(Bb + row * 128 + ((kk * 64 + r4 * 16) ^ cxor));
  }
#pragma unroll
  for (int fm = 0; fm < FM; ++fm) {
    int row = wbM + fm * 16 + r16;
    bf16x8 a0 = *(const bf16x8*)(Ab + row * 128 + ((r4 * 16) ^ cxor));
    bf16x8 a1 = *(const bf16x8*)(Ab + row * 128 + ((64 + r4 * 16) ^ cxor));
#pragma unroll
    for (int fn = 0; fn < FN; ++fn) {
      acc[fm][fn] = __builtin_amdgcn_mfma_f32_16x16x32_bf16(a0, bf[fn][0], acc[fm][fn], 0, 0, 0);
      acc[fm][fn] = __builtin_amdgcn_mfma_f32_16x16x32_bf16(a1, bf[fn][1], acc[fm][fn], 0, 0, 0);
    }
  }
}

// ---------------- fused x-convert + QKV GEMM (A fp32 -> bf16 in regs) --------
__global__ __launch_bounds__(256) void gemmq_kernel(
    const float* __restrict__ A, const __hip_bfloat16* __restrict__ Bt,
    const float* __restrict__ bias,
    void* __restrict__ o0, void* __restrict__ o1, void* __restrict__ o2) {
  __shared__ __align__(16) char smem[2][2][16384];  // [buf][A|B][128 rows x 128B]

  int tid = threadIdx.x, lane = tid & 63, wave = tid >> 6;
  int r16 = lane & 15, r4 = lane >> 4;

  int nwg = gridDim.x;
  int wg = (blockIdx.x & 7) * (nwg >> 3) + (blockIdx.x >> 3);
  int tileM = (wg / 12) * 128, tileN = (wg % 12) * 128;

  int wr = wave >> 1, wc = wave & 1;
  int wbM = wr * 64, wbN = wc * 64;

  const int rbase = tid >> 3, c = tid & 7;
  const int cs = (c ^ (rbase & 7)) << 4;
  const char* Ag = (const char*)A + (size_t)(tileM + rbase) * 2048 + c * 32;  // fp32
  const char* Bg = (const char*)Bt + (size_t)(tileN + rbase) * 1024 + c * 16;

  f32x4 acc[4][4] = {};
  f32x4 rAf[8];
  bf16x8 rB[4];

#pragma unroll
  for (int j = 0; j < 4; ++j) {
    rAf[2 * j]     = *(const f32x4*)(Ag + (size_t)j * 65536);
    rAf[2 * j + 1] = *(const f32x4*)(Ag + (size_t)j * 65536 + 16);
    rB[j] = *(const bf16x8*)(Bg + (size_t)j * 32768);
  }
#pragma unroll
  for (int j = 0; j < 4; ++j) {
    *(bf16x8*)(&smem[0][0][0] + (rbase + 32 * j) * 128 + cs) = cvt8(rAf[2 * j], rAf[2 * j + 1]);
    *(bf16x8*)(&smem[0][1][0] + (rbase + 32 * j) * 128 + cs) = rB[j];
  }
  __syncthreads();

#pragma unroll
  for (int kt = 0; kt < 8; ++kt) {
    int cur = kt & 1;
    if (kt < 7) {
#pragma unroll
      for (int j = 0; j < 4; ++j) {
        rAf[2 * j]     = *(const f32x4*)(Ag + (size_t)j * 65536 + (kt + 1) * 256);
        rAf[2 * j + 1] = *(const f32x4*)(Ag + (size_t)j * 65536 + (kt + 1) * 256 + 16);
        rB[j] = *(const bf16x8*)(Bg + (size_t)j * 32768 + (kt + 1) * 128);
      }
    }
    __builtin_amdgcn_s_setprio(1);
    compute_tile<4, 4>(&smem[cur][0][0], &smem[cur][1][0], wbM, wbN, r16, r4, acc);
    __builtin_amdgcn_s_setprio(0);
    if (kt < 7) {
#pragma unroll
      for (int j = 0; j < 4; ++j) {
        *(bf16x8*)(&smem[cur ^ 1][0][0] + (rbase + 32 * j) * 128 + cs) = cvt8(rAf[2 * j], rAf[2 * j + 1]);
        *(bf16x8*)(&smem[cur ^ 1][1][0] + (rbase + 32 * j) * 128 + cs) = rB[j];
      }
    }
    __syncthreads();
  }

  // bounce epilogue -> q/k/v row-major
  {
    char* scratch = &smem[0][0][0] + wave * 2304;      // 16 rows x 144B
    int gn0 = tileN + wbN;
    int sel = gn0 >> 9;
    int hh = (gn0 & 511) >> 6;
    __hip_bfloat16* obase = (sel == 0) ? (__hip_bfloat16*)o0
                          : (sel == 1) ? (__hip_bfloat16*)o1 : (__hip_bfloat16*)o2;
#pragma unroll
    for (int fm = 0; fm < 4; ++fm) {
#pragma unroll
      for (int fn = 0; fn < 4; ++fn) {
        float bv = bias[gn0 + fn * 16 + r16];
#pragma unroll
        for (int rr = 0; rr < 4; ++rr)
          *(__hip_bfloat16*)(scratch + (r4 * 4 + rr) * 144 + (fn * 16 + r16) * 2) =
              __float2bfloat16(acc[fm][fn][rr] + bv);
      }
#pragma unroll
      for (int p = 0; p < 2; ++p) {
        bf16x8 vrow = *(const bf16x8*)(scratch + (p * 8 + (lane >> 3)) * 144 + (lane & 7) * 16);
        int gm = tileM + wbM + fm * 16 + p * 8 + (lane >> 3);
        int bb = gm / 87, tt = gm - bb * 87;
        *(bf16x8*)(obase + ((size_t)(bb * 8 + hh) * 96 + tt) * 64 + (lane & 7) * 8) = vrow;
      }
    }
  }
}

// ---------------- proj GEMM (bf16 A, fp32 out) -------------------------------
__global__ __launch_bounds__(256) void gemmr_kernel(
    const __hip_bfloat16* __restrict__ A, const __hip_bfloat16* __restrict__ Bt,
    const float* __restrict__ bias, int ntn, float* __restrict__ out) {
  __shared__ __align__(16) char smem[2][2][16384];

  int tid = threadIdx.x, lane = tid & 63, wave = tid >> 6;
  int r16 = lane & 15, r4 = lane >> 4;

  int nwg = gridDim.x;
  int wg = (blockIdx.x & 7) * (nwg >> 3) + (blockIdx.x >> 3);
  int tileM = (wg / ntn) * 128, tileN = (wg % ntn) * 128;

  int wr = wave >> 1, wc = wave & 1;
  int wbM = wr * 64, wbN = wc * 64;

  const int rbase = tid >> 3, c = tid & 7;
  const int cs = (c ^ (rbase & 7)) << 4;
  const char* Ag = (const char*)A + (size_t)(tileM + rbase) * 1024 + c * 16;
  const char* Bg = (const char*)Bt + (size_t)(tileN + rbase) * 1024 + c * 16;

  f32x4 acc[4][4] = {};
  bf16x8 rA[4], rB[4];

#pragma unroll
  for (int j = 0; j < 4; ++j) {
    rA[j] = *(const bf16x8*)(Ag + (size_t)j * 32768);
    rB[j] = *(const bf16x8*)(Bg + (size_t)j * 32768);
  }
#pragma unroll
  for (int j = 0; j < 4; ++j) {
    *(bf16x8*)(&smem[0][0][0] + (rbase + 32 * j) * 128 + cs) = rA[j];
    *(bf16x8*)(&smem[0][1][0] + (rbase + 32 * j) * 128 + cs) = rB[j];
  }
  __syncthreads();

#pragma unroll
  for (int kt = 0; kt < 8; ++kt) {
    int cur = kt & 1;
    if (kt < 7) {
#pragma unroll
      for (int j = 0; j < 4; ++j) {
        rA[j] = *(const bf16x8*)(Ag + (size_t)j * 32768 + (kt + 1) * 128);
        rB[j] = *(const bf16x8*)(Bg + (size_t)j * 32768 + (kt + 1) * 128);
      }
    }
    __builtin_amdgcn_s_setprio(1);
    compute_tile<4, 4>(&smem[cur][0][0], &smem[cur][1][0], wbM, wbN, r16, r4, acc);
    __builtin_amdgcn_s_setprio(0);
    if (kt < 7) {
#pragma unroll
      for (int j = 0; j < 4; ++j) {
        *(bf16x8*)(&smem[cur ^ 1][0][0] + (rbase + 32 * j) * 128 + cs) = rA[j];
        *(bf16x8*)(&smem[cur ^ 1][1][0] + (rbase + 32 * j) * 128 + cs) = rB[j];
      }
    }
    __syncthreads();
  }

  {
    char* scratch = &smem[0][0][0] + wave * 4352;      // 16 rows x 272B
#pragma unroll
    for (int fm = 0; fm < 4; ++fm) {
#pragma unroll
      for (int fn = 0; fn < 4; ++fn) {
        float bv = bias[tileN + wbN + fn * 16 + r16];
#pragma unroll
        for (int rr = 0; rr < 4; ++rr)
          *(float*)(scratch + (r4 * 4 + rr) * 272 + (fn * 16 + r16) * 4) =
              acc[fm][fn][rr] + bv;
      }
#pragma unroll
      for (int p = 0; p < 4; ++p) {
        f32x4 vr = *(const f32x4*)(scratch + (p * 4 + (lane >> 4)) * 272 + (lane & 15) * 16);
        int gm = tileM + wbM + fm * 16 + p * 4 + (lane >> 4);
        *(f32x4*)(out + (size_t)gm * 512 + tileN + wbN + (lane & 15) * 4) = vr;
      }
    }
  }
}

// ---------------- attention per (b,h): in-reg softmax + y bounce -------------
// LDS: Qs[96 x 144B] @0 (later reused as Y scratch 96 x 136B) ; Ks @13824 ;
// Vt[64 x 208B, chunk^=(d>>3)&3] @27648 ; Pb[96 x 208B] @40960. 60928 B.
#define QS_O  0
#define KS_O  13824
#define VT_O  27648
#define PB_O  40960

__global__ __launch_bounds__(256) void attn_kernel(
    const __hip_bfloat16* __restrict__ q_ws, const __hip_bfloat16* __restrict__ k_ws,
    const __hip_bfloat16* __restrict__ v_ws, __hip_bfloat16* __restrict__ y_ws) {
  __shared__ __align__(16) char smem[60928];

  int tid = threadIdx.x, lane = tid & 63, wave = tid >> 6;
  int bh = blockIdx.x, b = bh >> 3, h = bh & 7;
  int r16 = lane & 15, r4 = lane >> 4;

  {
    const bf16x8* gq = (const bf16x8*)(q_ws + (size_t)bh * 6144);
    const bf16x8* gk = (const bf16x8*)(k_ws + (size_t)bh * 6144);
    const bf16x8* gv = (const bf16x8*)(v_ws + (size_t)bh * 6144);
    for (int i = tid; i < 768; i += 256) {
      int row = i >> 3, ch = i & 7;
      *(bf16x8*)(smem + QS_O + row * 144 + ch * 16) = gq[i];
      *(bf16x8*)(smem + KS_O + row * 144 + ch * 16) = gk[i];
      bf16x8 v8 = gv[i];
      int tc = row >> 3, tb = (row & 7) << 1, xr = ch & 3;
#pragma unroll
      for (int e = 0; e < 8; ++e) {
        int d = ch * 8 + e;
        *(__bf16*)(smem + VT_O + d * 208 + ((tc ^ xr) << 4) + tb) = v8[e];
      }
    }
  }
  __syncthreads();

  int ljv[6]; bool cok[6];
#pragma unroll
  for (int j = 0; j < 6; ++j) {
    int col = j * 16 + r16;
    ljv[j] = mod29(col);
    cok[j] = col < 87;
  }

  // QK^T + in-register masked softmax -> P
  for (int m = wave; m < 6; m += 4) {
    f32x4 s[6] = {};
#pragma unroll
    for (int kk = 0; kk < 2; ++kk) {
      bf16x8 aq = *(const bf16x8*)(smem + QS_O + (m * 16 + r16) * 144 + kk * 64 + r4 * 16);
#pragma unroll
      for (int j = 0; j < 6; ++j) {
        bf16x8 kb = *(const bf16x8*)(smem + KS_O + (j * 16 + r16) * 144 + kk * 64 + r4 * 16);
        s[j] = __builtin_amdgcn_mfma_f32_16x16x32_bf16(aq, kb, s[j], 0, 0, 0);
      }
    }
#pragma unroll
    for (int rr = 0; rr < 4; ++rr) {
      int row = m * 16 + r4 * 4 + rr;
      bool rok = row < 87;
      int lr = mod29(row);
      float mxv = -1e30f;
#pragma unroll
      for (int j = 0; j < 6; ++j) {
        bool al = rok && cok[j] && (ljv[j] <= lr) && (ljv[j] + 21 >= lr);
        float sv = al ? s[j][rr] * 0.125f : -1e30f;
        s[j][rr] = sv;
        mxv = fmaxf(mxv, sv);
      }
      mxv = fmaxf(mxv, __shfl_xor(mxv, 1));
      mxv = fmaxf(mxv, __shfl_xor(mxv, 2));
      mxv = fmaxf(mxv, __shfl_xor(mxv, 4));
      mxv = fmaxf(mxv, __shfl_xor(mxv, 8));
      float sm = 0.f;
#pragma unroll
      for (int j = 0; j < 6; ++j) {
        float e = __expf(s[j][rr] - mxv);
        s[j][rr] = e;
        sm += e;
      }
      sm += __shfl_xor(sm, 1);
      sm += __shfl_xor(sm, 2);
      sm += __shfl_xor(sm, 4);
      sm += __shfl_xor(sm, 8);
      float inv = rok ? 1.f / sm : 0.f;
#pragma unroll
      for (int j = 0; j < 6; ++j)
        *(__hip_bfloat16*)(smem + PB_O + row * 208 + (j * 16 + r16) * 2) =
            __float2bfloat16(s[j][rr] * inv);
    }
  }
  __syncthreads();   // P visible; QS region now dead -> reuse as Y scratch

  // Y = P V -> LDS scratch (pitch 136B, banks spread via r4 rows)
  for (int p = 0; p < 6; ++p) {
    int pair = wave + p * 4;
    int mt = pair >> 2, nt = pair & 3;
    int d = nt * 16 + r16;
    int dx = (d >> 3) & 3;
    f32x4 acc = {0.f, 0.f, 0.f, 0.f};
#pragma unroll
    for (int kk = 0; kk < 3; ++kk) {
      bf16x8 a  = *(const bf16x8*)(smem + PB_O + (mt * 16 + r16) * 208 + kk * 64 + r4 * 16);
      bf16x8 bb = *(const bf16x8*)(smem + VT_O + d * 208 + (((kk * 4 + r4) ^ dx) << 4));
      acc = __builtin_amdgcn_mfma_f32_16x16x32_bf16(a, bb, acc, 0, 0, 0);
    }
    int t0 = mt * 16 + r4 * 4;
#pragma unroll
    for (int r = 0; r < 4; ++r)
      *(__bf16*)(smem + QS_O + (t0 + r) * 136 + d * 2) =
          __builtin_bit_cast(__bf16, (unsigned short)__builtin_bit_cast(unsigned short, __float2bfloat16(acc[r])));
  }
  __syncthreads();

  // coalesced y store: 8 lanes cover one 128B row-slice
  for (int i = tid; i < 768; i += 256) {
    int row = i >> 3, ch = i & 7;
    if (row < 87) {
      bf16x8 vrow = *(const bf16x8*)(smem + QS_O + row * 136 + ch * 16);
      *(bf16x8*)((char*)y_ws + ((size_t)b * 87 + row) * 1024 + h * 128 + ch * 16) = vrow;
    }
  }
}

// ---------------- launch ----------------
extern "C" void kernel_launch(void* const* d_in, const int* in_sizes, int n_in,
                              void* d_out, int out_size, void* d_ws, size_t ws_size,
                              hipStream_t stream) {
  const float* x  = (const float*)d_in[0];
  const float* Wq = (const float*)d_in[1];
  const float* bq = (const float*)d_in[2];
  const float* Wk = (const float*)d_in[3];
  const float* bk = (const float*)d_in[4];
  const float* Wv = (const float*)d_in[5];
  const float* bv = (const float*)d_in[6];
  const float* Wp = (const float*)d_in[7];
  const float* bp = (const float*)d_in[8];
  float* out = (float*)d_out;

  char* ws = (char*)d_ws;
  size_t off = 0;
  __hip_bfloat16* yb    = (__hip_bfloat16*)(ws + off); off += (size_t)BT_ * 512 * 2;
  __hip_bfloat16* wqkv  = (__hip_bfloat16*)(ws + off); off += 1536 * 512 * 2;
  __hip_bfloat16* wp    = (__hip_bfloat16*)(ws + off); off += 512 * 512 * 2;
  float*          biasc = (float*)(ws + off);          off += 8192;
  __hip_bfloat16* q_ws  = (__hip_bfloat16*)(ws + off); off += (size_t)BH_ * 6144 * 2;
  __hip_bfloat16* k_ws  = (__hip_bfloat16*)(ws + off); off += (size_t)BH_ * 6144 * 2;
  __hip_bfloat16* v_ws  = (__hip_bfloat16*)(ws + off); off += (size_t)BH_ * 6144 * 2;

  if (ws_size < off) return;

  convert_w_kernel<<<1024, 256, 0, stream>>>(Wq, Wk, Wv, Wp, bq, bk, bv, wqkv, wp, biasc);
  // qkv (x fp32 read directly): 128x128 tiles -> 348 x 12 = 4176 blocks
  gemmq_kernel<<<4176, 256, 0, stream>>>(x, wqkv, biasc, q_ws, k_ws, v_ws);
  attn_kernel<<<BH_, 256, 0, stream>>>(q_ws, k_ws, v_ws, yb);
  // proj: 128x128 tiles -> 348 x 4 = 1392 blocks
  gemmr_kernel<<<1392, 256, 0, stream>>>(yb, wp, bp, 4, out);
}

// Round 13
// 248.966 us; speedup vs baseline: 1.0815x; 1.0815x over previous
//
#include <hip/hip_runtime.h>
#include <hip/hip_bf16.h>
#include <stdint.h>

// Problem constants
#define B_   512
#define T_   87
#define C_   512
#define H_   8
#define D_   64
#define BT_  44544        // B_*T_
#define BH_  4096         // B_*H_

typedef __attribute__((ext_vector_type(4))) float f32x4;
typedef __attribute__((ext_vector_type(8))) __bf16 bf16x8;
typedef __attribute__((ext_vector_type(4))) unsigned short u16x4;

__device__ __forceinline__ void gl_lds16(const void* g, void* l) {
  __builtin_amdgcn_global_load_lds(
      (const __attribute__((address_space(1))) unsigned int*)g,
      (__attribute__((address_space(3))) unsigned int*)l, 16, 0, 0);
}

template<int N>
__device__ __forceinline__ void waitv() {
  asm volatile("s_waitcnt vmcnt(%0)" :: "i"(N) : "memory");
}

__device__ __forceinline__ int mod29(int x) {
  return x < 29 ? x : (x < 58 ? x - 29 : x - 58);
}

// ---------------- converts ----------------

__global__ void convert_x_kernel(const float* __restrict__ x,
                                 __hip_bfloat16* __restrict__ xb, int n4) {
  int stride = gridDim.x * blockDim.x;
  for (int i = blockIdx.x * blockDim.x + threadIdx.x; i < n4; i += stride) {
    f32x4 v = ((const f32x4*)x)[i];
    u16x4 o;
    o.x = __builtin_bit_cast(unsigned short, __float2bfloat16(v.x));
    o.y = __builtin_bit_cast(unsigned short, __float2bfloat16(v.y));
    o.z = __builtin_bit_cast(unsigned short, __float2bfloat16(v.z));
    o.w = __builtin_bit_cast(unsigned short, __float2bfloat16(v.w));
    ((u16x4*)xb)[i] = o;
  }
}

__global__ void convert_w_kernel(const float* __restrict__ Wq, const float* __restrict__ Wk,
                                 const float* __restrict__ Wv, const float* __restrict__ Wp,
                                 const float* __restrict__ bq, const float* __restrict__ bk,
                                 const float* __restrict__ bv,
                                 __hip_bfloat16* __restrict__ wqkv,
                                 __hip_bfloat16* __restrict__ wp,
                                 float* __restrict__ biasc) {
  const int NW = 262144;                 // 512*512
  const int total = 3 * NW + NW + 1536;
  int stride = gridDim.x * blockDim.x;
  for (int i = blockIdx.x * blockDim.x + threadIdx.x; i < total; i += stride) {
    if (i < 3 * NW) {
      float v = (i < NW) ? Wq[i] : (i < 2 * NW ? Wk[i - NW] : Wv[i - 2 * NW]);
      wqkv[i] = __float2bfloat16(v);
    } else if (i < 4 * NW) {
      wp[i - 3 * NW] = __float2bfloat16(Wp[i - 3 * NW]);
    } else {
      int j = i - 4 * NW;
      biasc[j] = (j < 512) ? bq[j] : (j < 1024 ? bk[j - 512] : bv[j - 1024]);
    }
  }
}

// ---------------- 8-phase-style GEMM core (BK=32, 256x256, 8 waves) ----------
// (R8 main loop, verified correct) + R10 bounce epilogue.
// LDS slot (32KB) = A panel [256 x 64B] + B panel [256 x 64B]; chunk s of row
// r holds global chunk s^((r>>1)&3) -> 2-way bank aliasing only (free, m136).
// Ring of 4 slots, stage distance 2 K-tiles, counted vmcnt(4).

__device__ __forceinline__ void stage_panel(const char* g, int kbyte, char* dst,
                                            int wave, int lane) {
  int rl = lane >> 2, s = lane & 3;
#pragma unroll
  for (int j = 0; j < 2; ++j) {
    int rbase = j * 128 + wave * 16;
    int row = rbase + rl;
    int colsw = ((s ^ ((row >> 1) & 3)) << 4);
    gl_lds16(g + (size_t)row * 1024 + kbyte + colsw, dst + rbase * 64);
  }
}

#define PHASE_SEP() __builtin_amdgcn_sched_barrier(0)

// EPI 0: qkv row-major outputs (o0=q,o1=k,o2=v, bias=biasc). EPI 1: proj fp32.
template<int EPI>
__global__ __launch_bounds__(512, 2) void gemm8_kernel(
    const __hip_bfloat16* __restrict__ A, const __hip_bfloat16* __restrict__ Bt,
    const float* __restrict__ bias, int ntn,
    void* __restrict__ o0, void* __restrict__ o1, void* __restrict__ o2) {
  constexpr int SLOT = 32768;
  constexpr int BOFF = 16384;
  __shared__ __align__(16) char smem[4 * SLOT];

  int tid = threadIdx.x, lane = tid & 63, wave = tid >> 6;
  int r16 = lane & 15, r4 = lane >> 4;

  // bijective XCD swizzle (m204)
  int nwg = gridDim.x;
  int xcd = blockIdx.x & 7, idx = blockIdx.x >> 3;
  int q8 = nwg >> 3, r8 = nwg & 7;
  int wg = (xcd < r8 ? xcd * (q8 + 1) : r8 * (q8 + 1) + (xcd - r8) * q8) + idx;
  int tileM = (wg / ntn) * 256, tileN = (wg % ntn) * 256;

  int wr = wave >> 2, wc = wave & 3;       // 2M x 4N; per-wave 128 x 64
  int wbM = wr * 128, wbN = wc * 64;

  f32x4 acc[8][4] = {};

  const char* Ag = (const char*)A + (size_t)tileM * 1024;
  const char* Bg = (const char*)Bt + (size_t)tileN * 1024;

  int arow[8], brow[4];
#pragma unroll
  for (int fm = 0; fm < 8; ++fm) arow[fm] = wbM + fm * 16 + r16;
#pragma unroll
  for (int fn = 0; fn < 4; ++fn) brow[fn] = wbN + fn * 16 + r16;

  // prologue: stage K-tiles 0,1 into slots 0,1 (8 loads outstanding)
  stage_panel(Ag, 0, smem, wave, lane);
  stage_panel(Bg, 0, smem + BOFF, wave, lane);
  stage_panel(Ag, 64, smem + SLOT, wave, lane);
  stage_panel(Bg, 64, smem + SLOT + BOFF, wave, lane);

#pragma unroll
  for (int kt = 0; kt < 16; ++kt) {
    if (kt < 15) waitv<4>(); else waitv<0>();
    PHASE_SEP();
    __builtin_amdgcn_s_barrier();
    PHASE_SEP();

    const char* cb = smem + (kt & 3) * SLOT;
    char* nb = smem + ((kt + 2) & 3) * SLOT;
    bool st = kt < 14;

    // phase 1: read B fn0-3 + A fm0-3 ; stage A(kt+2) ; 16 MFMA
    bf16x8 bfr[4], afr[4];
#pragma unroll
    for (int fn = 0; fn < 4; ++fn)
      bfr[fn] = *(const bf16x8*)(cb + BOFF + brow[fn] * 64 +
                                 ((r4 ^ ((brow[fn] >> 1) & 3)) << 4));
#pragma unroll
    for (int fm = 0; fm < 4; ++fm)
      afr[fm] = *(const bf16x8*)(cb + arow[fm] * 64 +
                                 ((r4 ^ ((arow[fm] >> 1) & 3)) << 4));
    if (st) stage_panel(Ag, (kt + 2) * 64, nb, wave, lane);
    PHASE_SEP();
    __builtin_amdgcn_s_barrier();
    asm volatile("s_waitcnt lgkmcnt(0)" ::: "memory");
    PHASE_SEP();
    __builtin_amdgcn_s_setprio(1);
#pragma unroll
    for (int fm = 0; fm < 4; ++fm)
#pragma unroll
      for (int fn = 0; fn < 4; ++fn)
        acc[fm][fn] = __builtin_amdgcn_mfma_f32_16x16x32_bf16(afr[fm], bfr[fn],
                                                              acc[fm][fn], 0, 0, 0);
    __builtin_amdgcn_s_setprio(0);
    PHASE_SEP();
    __builtin_amdgcn_s_barrier();
    PHASE_SEP();

    // phase 2: read A fm4-7 ; stage B(kt+2) ; 16 MFMA
    bf16x8 afr2[4];
#pragma unroll
    for (int fm = 0; fm < 4; ++fm)
      afr2[fm] = *(const bf16x8*)(cb + arow[fm + 4] * 64 +
                                  ((r4 ^ ((arow[fm + 4] >> 1) & 3)) << 4));
    if (st) stage_panel(Bg, (kt + 2) * 64, nb + BOFF, wave, lane);
    PHASE_SEP();
    __builtin_amdgcn_s_barrier();
    asm volatile("s_waitcnt lgkmcnt(0)" ::: "memory");
    PHASE_SEP();
    __builtin_amdgcn_s_setprio(1);
#pragma unroll
    for (int fm = 0; fm < 4; ++fm)
#pragma unroll
      for (int fn = 0; fn < 4; ++fn)
        acc[fm + 4][fn] = __builtin_amdgcn_mfma_f32_16x16x32_bf16(afr2[fm], bfr[fn],
                                                                  acc[fm + 4][fn], 0, 0, 0);
    __builtin_amdgcn_s_setprio(0);
    PHASE_SEP();
    __builtin_amdgcn_s_barrier();
    PHASE_SEP();
  }

  // ---- bounce epilogue (R10): frag -> per-wave LDS scratch -> coalesced ----
  if constexpr (EPI == 0) {
    char* scratch = smem + wave * 2304;                // 16 rows x 144B
    int gn0 = tileN + wbN;                             // head-aligned
    int sel = gn0 >> 9;
    int hh = (gn0 & 511) >> 6;
    __hip_bfloat16* obase = (sel == 0) ? (__hip_bfloat16*)o0
                          : (sel == 1) ? (__hip_bfloat16*)o1 : (__hip_bfloat16*)o2;
#pragma unroll
    for (int fm = 0; fm < 8; ++fm) {
#pragma unroll
      for (int fn = 0; fn < 4; ++fn) {
        float bv = bias[gn0 + fn * 16 + r16];
#pragma unroll
        for (int rr = 0; rr < 4; ++rr)
          *(__hip_bfloat16*)(scratch + (r4 * 4 + rr) * 144 + (fn * 16 + r16) * 2) =
              __float2bfloat16(acc[fm][fn][rr] + bv);
      }
#pragma unroll
      for (int p = 0; p < 2; ++p) {
        bf16x8 vrow = *(const bf16x8*)(scratch + (p * 8 + (lane >> 3)) * 144 + (lane & 7) * 16);
        int gm = tileM + wbM + fm * 16 + p * 8 + (lane >> 3);
        int bb = gm / 87, tt = gm - bb * 87;
        *(bf16x8*)(obase + ((size_t)(bb * 8 + hh) * 96 + tt) * 64 + (lane & 7) * 8) = vrow;
      }
    }
  } else {
    char* scratch = smem + wave * 4352;                // 16 rows x 272B
#pragma unroll
    for (int fm = 0; fm < 8; ++fm) {
#pragma unroll
      for (int fn = 0; fn < 4; ++fn) {
        float bv = bias[tileN + wbN + fn * 16 + r16];
#pragma unroll
        for (int rr = 0; rr < 4; ++rr)
          *(float*)(scratch + (r4 * 4 + rr) * 272 + (fn * 16 + r16) * 4) =
              acc[fm][fn][rr] + bv;
      }
#pragma unroll
      for (int p = 0; p < 4; ++p) {
        f32x4 vr = *(const f32x4*)(scratch + (p * 4 + (lane >> 4)) * 272 + (lane & 15) * 16);
        int gm = tileM + wbM + fm * 16 + p * 4 + (lane >> 4);
        *(f32x4*)((float*)o0 + (size_t)gm * 512 + tileN + wbN + (lane & 15) * 4) = vr;
      }
    }
  }
}

// ---------------- attention per (b,h) (R12 version, y-bounce) ----------------
#define QS_O  0
#define KS_O  13824
#define VT_O  27648
#define PB_O  40960

__global__ __launch_bounds__(256) void attn_kernel(
    const __hip_bfloat16* __restrict__ q_ws, const __hip_bfloat16* __restrict__ k_ws,
    const __hip_bfloat16* __restrict__ v_ws, __hip_bfloat16* __restrict__ y_ws) {
  __shared__ __align__(16) char smem[60928];

  int tid = threadIdx.x, lane = tid & 63, wave = tid >> 6;
  int bh = blockIdx.x, b = bh >> 3, h = bh & 7;
  int r16 = lane & 15, r4 = lane >> 4;

  {
    const bf16x8* gq = (const bf16x8*)(q_ws + (size_t)bh * 6144);
    const bf16x8* gk = (const bf16x8*)(k_ws + (size_t)bh * 6144);
    const bf16x8* gv = (const bf16x8*)(v_ws + (size_t)bh * 6144);
    for (int i = tid; i < 768; i += 256) {
      int row = i >> 3, ch = i & 7;
      *(bf16x8*)(smem + QS_O + row * 144 + ch * 16) = gq[i];
      *(bf16x8*)(smem + KS_O + row * 144 + ch * 16) = gk[i];
      bf16x8 v8 = gv[i];
      int tc = row >> 3, tb = (row & 7) << 1, xr = ch & 3;
#pragma unroll
      for (int e = 0; e < 8; ++e) {
        int d = ch * 8 + e;
        *(__bf16*)(smem + VT_O + d * 208 + ((tc ^ xr) << 4) + tb) = v8[e];
      }
    }
  }
  __syncthreads();

  int ljv[6]; bool cok[6];
#pragma unroll
  for (int j = 0; j < 6; ++j) {
    int col = j * 16 + r16;
    ljv[j] = mod29(col);
    cok[j] = col < 87;
  }

  for (int m = wave; m < 6; m += 4) {
    f32x4 s[6] = {};
#pragma unroll
    for (int kk = 0; kk < 2; ++kk) {
      bf16x8 aq = *(const bf16x8*)(smem + QS_O + (m * 16 + r16) * 144 + kk * 64 + r4 * 16);
#pragma unroll
      for (int j = 0; j < 6; ++j) {
        bf16x8 kb = *(const bf16x8*)(smem + KS_O + (j * 16 + r16) * 144 + kk * 64 + r4 * 16);
        s[j] = __builtin_amdgcn_mfma_f32_16x16x32_bf16(aq, kb, s[j], 0, 0, 0);
      }
    }
#pragma unroll
    for (int rr = 0; rr < 4; ++rr) {
      int row = m * 16 + r4 * 4 + rr;
      bool rok = row < 87;
      int lr = mod29(row);
      float mxv = -1e30f;
#pragma unroll
      for (int j = 0; j < 6; ++j) {
        bool al = rok && cok[j] && (ljv[j] <= lr) && (ljv[j] + 21 >= lr);
        float sv = al ? s[j][rr] * 0.125f : -1e30f;
        s[j][rr] = sv;
        mxv = fmaxf(mxv, sv);
      }
      mxv = fmaxf(mxv, __shfl_xor(mxv, 1));
      mxv = fmaxf(mxv, __shfl_xor(mxv, 2));
      mxv = fmaxf(mxv, __shfl_xor(mxv, 4));
      mxv = fmaxf(mxv, __shfl_xor(mxv, 8));
      float sm = 0.f;
#pragma unroll
      for (int j = 0; j < 6; ++j) {
        float e = __expf(s[j][rr] - mxv);
        s[j][rr] = e;
        sm += e;
      }
      sm += __shfl_xor(sm, 1);
      sm += __shfl_xor(sm, 2);
      sm += __shfl_xor(sm, 4);
      sm += __shfl_xor(sm, 8);
      float inv = rok ? 1.f / sm : 0.f;
#pragma unroll
      for (int j = 0; j < 6; ++j)
        *(__hip_bfloat16*)(smem + PB_O + row * 208 + (j * 16 + r16) * 2) =
            __float2bfloat16(s[j][rr] * inv);
    }
  }
  __syncthreads();

  for (int p = 0; p < 6; ++p) {
    int pair = wave + p * 4;
    int mt = pair >> 2, nt = pair & 3;
    int d = nt * 16 + r16;
    int dx = (d >> 3) & 3;
    f32x4 acc = {0.f, 0.f, 0.f, 0.f};
#pragma unroll
    for (int kk = 0; kk < 3; ++kk) {
      bf16x8 a  = *(const bf16x8*)(smem + PB_O + (mt * 16 + r16) * 208 + kk * 64 + r4 * 16);
      bf16x8 bb = *(const bf16x8*)(smem + VT_O + d * 208 + (((kk * 4 + r4) ^ dx) << 4));
      acc = __builtin_amdgcn_mfma_f32_16x16x32_bf16(a, bb, acc, 0, 0, 0);
    }
    int t0 = mt * 16 + r4 * 4;
#pragma unroll
    for (int r = 0; r < 4; ++r)
      *(__bf16*)(smem + QS_O + (t0 + r) * 136 + d * 2) =
          __builtin_bit_cast(__bf16, __builtin_bit_cast(unsigned short, __float2bfloat16(acc[r])));
  }
  __syncthreads();

  for (int i = tid; i < 768; i += 256) {
    int row = i >> 3, ch = i & 7;
    if (row < 87) {
      bf16x8 vrow = *(const bf16x8*)(smem + QS_O + row * 136 + ch * 16);
      *(bf16x8*)((char*)y_ws + ((size_t)b * 87 + row) * 1024 + h * 128 + ch * 16) = vrow;
    }
  }
}

// ---------------- launch ----------------
extern "C" void kernel_launch(void* const* d_in, const int* in_sizes, int n_in,
                              void* d_out, int out_size, void* d_ws, size_t ws_size,
                              hipStream_t stream) {
  const float* x  = (const float*)d_in[0];
  const float* Wq = (const float*)d_in[1];
  const float* bq = (const float*)d_in[2];
  const float* Wk = (const float*)d_in[3];
  const float* bk = (const float*)d_in[4];
  const float* Wv = (const float*)d_in[5];
  const float* bv = (const float*)d_in[6];
  const float* Wp = (const float*)d_in[7];
  const float* bp = (const float*)d_in[8];
  float* out = (float*)d_out;

  char* ws = (char*)d_ws;
  size_t off = 0;
  __hip_bfloat16* xb    = (__hip_bfloat16*)(ws + off); off += (size_t)BT_ * 512 * 2;
  __hip_bfloat16* wqkv  = (__hip_bfloat16*)(ws + off); off += 1536 * 512 * 2;
  __hip_bfloat16* wp    = (__hip_bfloat16*)(ws + off); off += 512 * 512 * 2;
  float*          biasc = (float*)(ws + off);          off += 8192;
  __hip_bfloat16* q_ws  = (__hip_bfloat16*)(ws + off); off += (size_t)BH_ * 6144 * 2;
  __hip_bfloat16* k_ws  = (__hip_bfloat16*)(ws + off); off += (size_t)BH_ * 6144 * 2;
  __hip_bfloat16* v_ws  = (__hip_bfloat16*)(ws + off); off += (size_t)BH_ * 6144 * 2;
  __hip_bfloat16* yb = xb;  // alias: xb fully consumed by qkv before attn writes y

  if (ws_size < off) return;

  convert_x_kernel<<<2048, 256, 0, stream>>>(x, xb, BT_ * 512 / 4);
  convert_w_kernel<<<1024, 256, 0, stream>>>(Wq, Wk, Wv, Wp, bq, bk, bv, wqkv, wp, biasc);
  // qkv: 256x256 tiles -> 174 x 6 = 1044 blocks
  gemm8_kernel<0><<<1044, 512, 0, stream>>>(xb, wqkv, biasc, 6, q_ws, k_ws, v_ws);
  attn_kernel<<<BH_, 256, 0, stream>>>(q_ws, k_ws, v_ws, yb);
  // proj: 256x256 tiles -> 174 x 2 = 348 blocks
  gemm8_kernel<1><<<348, 512, 0, stream>>>(yb, wp, bp, 2, out, nullptr, nullptr);
}

// Round 14
// 240.314 us; speedup vs baseline: 1.1204x; 1.0360x over previous
//
#include <hip/hip_runtime.h>
#include <hip/hip_bf16.h>
#include <stdint.h>

// Problem constants
#define B_   512
#define T_   87
#define C_   512
#define H_   8
#define D_   64
#define BT_  44544        // B_*T_
#define BH_  4096         // B_*H_

typedef __attribute__((ext_vector_type(4))) float f32x4;
typedef __attribute__((ext_vector_type(8))) __bf16 bf16x8;
typedef __attribute__((ext_vector_type(4))) unsigned short u16x4;

__device__ __forceinline__ int mod29(int x) {
  return x < 29 ? x : (x < 58 ? x - 29 : x - 58);
}

// ---------------- converts ----------------

__global__ void convert_x_kernel(const float* __restrict__ x,
                                 __hip_bfloat16* __restrict__ xb, int n4) {
  int stride = gridDim.x * blockDim.x;
  for (int i = blockIdx.x * blockDim.x + threadIdx.x; i < n4; i += stride) {
    f32x4 v = ((const f32x4*)x)[i];
    u16x4 o;
    o.x = __builtin_bit_cast(unsigned short, __float2bfloat16(v.x));
    o.y = __builtin_bit_cast(unsigned short, __float2bfloat16(v.y));
    o.z = __builtin_bit_cast(unsigned short, __float2bfloat16(v.z));
    o.w = __builtin_bit_cast(unsigned short, __float2bfloat16(v.w));
    ((u16x4*)xb)[i] = o;
  }
}

__global__ void convert_w_kernel(const float* __restrict__ Wq, const float* __restrict__ Wk,
                                 const float* __restrict__ Wv, const float* __restrict__ Wp,
                                 const float* __restrict__ bq, const float* __restrict__ bk,
                                 const float* __restrict__ bv,
                                 __hip_bfloat16* __restrict__ wqkv,
                                 __hip_bfloat16* __restrict__ wp,
                                 float* __restrict__ biasc) {
  const int NW = 262144;                 // 512*512
  const int total = 3 * NW + NW + 1536;
  int stride = gridDim.x * blockDim.x;
  for (int i = blockIdx.x * blockDim.x + threadIdx.x; i < total; i += stride) {
    if (i < 3 * NW) {
      float v = (i < NW) ? Wq[i] : (i < 2 * NW ? Wk[i - NW] : Wv[i - 2 * NW]);
      wqkv[i] = __float2bfloat16(v);
    } else if (i < 4 * NW) {
      wp[i - 3 * NW] = __float2bfloat16(Wp[i - 3 * NW]);
    } else {
      int j = i - 4 * NW;
      biasc[j] = (j < 512) ? bq[j] : (j < 1024 ? bk[j - 512] : bv[j - 1024]);
    }
  }
}

// ---------------- reg-staged GEMM, 128x128, depth-2 register pipeline --------
// LDS: 2 buffers x (A 16KB + B 16KB) = 64KB -> 2 blocks/CU.
// Swizzle on ds_write: 16B slot s of row r holds global chunk s^(r&7).
// Depth-2: at iter kt, issue global loads for tile kt+2 (into reg set kt&1)
// and ds_write tile kt+1 (reg set (kt&1)^1, loaded at iter kt-1) -> load
// latency spans TWO compute phases.

template<int FM, int FN>
__device__ __forceinline__ void compute_tile(const char* Ab, const char* Bb,
                                             int wbM, int wbN, int r16, int r4,
                                             f32x4 acc[FM][FN]) {
  const int cxor = (r16 & 7) << 4;
  bf16x8 bf[FN][2];
#pragma unroll
  for (int fn = 0; fn < FN; ++fn) {
    int row = wbN + fn * 16 + r16;
#pragma unroll
    for (int kk = 0; kk < 2; ++kk)
      bf[fn][kk] = *(const bf16x8*)(Bb + row * 128 + ((kk * 64 + r4 * 16) ^ cxor));
  }
#pragma unroll
  for (int fm = 0; fm < FM; ++fm) {
    int row = wbM + fm * 16 + r16;
    bf16x8 a0 = *(const bf16x8*)(Ab + row * 128 + ((r4 * 16) ^ cxor));
    bf16x8 a1 = *(const bf16x8*)(Ab + row * 128 + ((64 + r4 * 16) ^ cxor));
#pragma unroll
    for (int fn = 0; fn < FN; ++fn) {
      acc[fm][fn] = __builtin_amdgcn_mfma_f32_16x16x32_bf16(a0, bf[fn][0], acc[fm][fn], 0, 0, 0);
      acc[fm][fn] = __builtin_amdgcn_mfma_f32_16x16x32_bf16(a1, bf[fn][1], acc[fm][fn], 0, 0, 0);
    }
  }
}

// EPI 0: qkv row-major outputs (o0=q,o1=k,o2=v, bias=biasc). EPI 1: proj fp32.
template<int EPI>
__global__ __launch_bounds__(256) void gemmr_kernel(
    const __hip_bfloat16* __restrict__ A, const __hip_bfloat16* __restrict__ Bt,
    const float* __restrict__ bias, int ntn,
    void* __restrict__ o0, void* __restrict__ o1, void* __restrict__ o2) {
  __shared__ __align__(16) char smem[2][2][16384];  // [buf][A|B][128 rows x 128B]

  int tid = threadIdx.x, lane = tid & 63, wave = tid >> 6;
  int r16 = lane & 15, r4 = lane >> 4;

  int nwg = gridDim.x;
  int wg = (blockIdx.x & 7) * (nwg >> 3) + (blockIdx.x >> 3);
  int tileM = (wg / ntn) * 128, tileN = (wg % ntn) * 128;

  int wr = wave >> 1, wc = wave & 1;       // per-wave 64x64
  int wbM = wr * 64, wbN = wc * 64;

  const int rbase = tid >> 3, c = tid & 7;
  const int cs = (c ^ (rbase & 7)) << 4;
  const char* Ag = (const char*)A + (size_t)(tileM + rbase) * 1024 + c * 16;
  const char* Bg = (const char*)Bt + (size_t)(tileN + rbase) * 1024 + c * 16;

  f32x4 acc[4][4] = {};
  bf16x8 sA[2][4], sB[2][4];

  // prologue: tile0 -> set0 -> LDS[0]; tile1 -> set1 (in flight)
#pragma unroll
  for (int j = 0; j < 4; ++j) {
    sA[0][j] = *(const bf16x8*)(Ag + (size_t)j * 32768);
    sB[0][j] = *(const bf16x8*)(Bg + (size_t)j * 32768);
  }
#pragma unroll
  for (int j = 0; j < 4; ++j) {
    *(bf16x8*)(&smem[0][0][0] + (rbase + 32 * j) * 128 + cs) = sA[0][j];
    *(bf16x8*)(&smem[0][1][0] + (rbase + 32 * j) * 128 + cs) = sB[0][j];
  }
#pragma unroll
  for (int j = 0; j < 4; ++j) {
    sA[1][j] = *(const bf16x8*)(Ag + (size_t)j * 32768 + 128);
    sB[1][j] = *(const bf16x8*)(Bg + (size_t)j * 32768 + 128);
  }
  __syncthreads();

#pragma unroll
  for (int kt = 0; kt < 8; ++kt) {
    const int cur = kt & 1;
    if (kt < 6) {   // issue tile kt+2 into set[cur] (its old tile is in LDS)
#pragma unroll
      for (int j = 0; j < 4; ++j) {
        sA[cur][j] = *(const bf16x8*)(Ag + (size_t)j * 32768 + (kt + 2) * 128);
        sB[cur][j] = *(const bf16x8*)(Bg + (size_t)j * 32768 + (kt + 2) * 128);
      }
    }
    __builtin_amdgcn_s_setprio(1);
    compute_tile<4, 4>(&smem[cur][0][0], &smem[cur][1][0], wbM, wbN, r16, r4, acc);
    __builtin_amdgcn_s_setprio(0);
    if (kt < 7) {   // write tile kt+1 (set[cur^1], loaded at iter kt-1)
#pragma unroll
      for (int j = 0; j < 4; ++j) {
        *(bf16x8*)(&smem[cur ^ 1][0][0] + (rbase + 32 * j) * 128 + cs) = sA[cur ^ 1][j];
        *(bf16x8*)(&smem[cur ^ 1][1][0] + (rbase + 32 * j) * 128 + cs) = sB[cur ^ 1][j];
      }
    }
    __syncthreads();
  }

  // ---- bounce epilogue: frag -> per-wave LDS scratch -> coalesced stores ----
  if constexpr (EPI == 0) {
    char* scratch = &smem[0][0][0] + wave * 2304;      // 16 rows x 144B
    int gn0 = tileN + wbN;                             // head-aligned
    int sel = gn0 >> 9;
    int hh = (gn0 & 511) >> 6;
    __hip_bfloat16* obase = (sel == 0) ? (__hip_bfloat16*)o0
                          : (sel == 1) ? (__hip_bfloat16*)o1 : (__hip_bfloat16*)o2;
#pragma unroll
    for (int fm = 0; fm < 4; ++fm) {
#pragma unroll
      for (int fn = 0; fn < 4; ++fn) {
        float bv = bias[gn0 + fn * 16 + r16];
#pragma unroll
        for (int rr = 0; rr < 4; ++rr)
          *(__hip_bfloat16*)(scratch + (r4 * 4 + rr) * 144 + (fn * 16 + r16) * 2) =
              __float2bfloat16(acc[fm][fn][rr] + bv);
      }
#pragma unroll
      for (int p = 0; p < 2; ++p) {
        bf16x8 vrow = *(const bf16x8*)(scratch + (p * 8 + (lane >> 3)) * 144 + (lane & 7) * 16);
        int gm = tileM + wbM + fm * 16 + p * 8 + (lane >> 3);
        int bb = gm / 87, tt = gm - bb * 87;
        *(bf16x8*)(obase + ((size_t)(bb * 8 + hh) * 96 + tt) * 64 + (lane & 7) * 8) = vrow;
      }
    }
  } else {
    char* scratch = &smem[0][0][0] + wave * 4352;      // 16 rows x 272B
#pragma unroll
    for (int fm = 0; fm < 4; ++fm) {
#pragma unroll
      for (int fn = 0; fn < 4; ++fn) {
        float bv = bias[tileN + wbN + fn * 16 + r16];
#pragma unroll
        for (int rr = 0; rr < 4; ++rr)
          *(float*)(scratch + (r4 * 4 + rr) * 272 + (fn * 16 + r16) * 4) =
              acc[fm][fn][rr] + bv;
      }
#pragma unroll
      for (int p = 0; p < 4; ++p) {
        f32x4 vr = *(const f32x4*)(scratch + (p * 4 + (lane >> 4)) * 272 + (lane & 15) * 16);
        int gm = tileM + wbM + fm * 16 + p * 4 + (lane >> 4);
        *(f32x4*)((float*)o0 + (size_t)gm * 512 + tileN + wbN + (lane & 15) * 4) = vr;
      }
    }
  }
}

// ---------------- attention per (b,h) (R12 version, y-bounce) ----------------
#define QS_O  0
#define KS_O  13824
#define VT_O  27648
#define PB_O  40960

__global__ __launch_bounds__(256) void attn_kernel(
    const __hip_bfloat16* __restrict__ q_ws, const __hip_bfloat16* __restrict__ k_ws,
    const __hip_bfloat16* __restrict__ v_ws, __hip_bfloat16* __restrict__ y_ws) {
  __shared__ __align__(16) char smem[60928];

  int tid = threadIdx.x, lane = tid & 63, wave = tid >> 6;
  int bh = blockIdx.x, b = bh >> 3, h = bh & 7;
  int r16 = lane & 15, r4 = lane >> 4;

  {
    const bf16x8* gq = (const bf16x8*)(q_ws + (size_t)bh * 6144);
    const bf16x8* gk = (const bf16x8*)(k_ws + (size_t)bh * 6144);
    const bf16x8* gv = (const bf16x8*)(v_ws + (size_t)bh * 6144);
    for (int i = tid; i < 768; i += 256) {
      int row = i >> 3, ch = i & 7;
      *(bf16x8*)(smem + QS_O + row * 144 + ch * 16) = gq[i];
      *(bf16x8*)(smem + KS_O + row * 144 + ch * 16) = gk[i];
      bf16x8 v8 = gv[i];
      int tc = row >> 3, tb = (row & 7) << 1, xr = ch & 3;
#pragma unroll
      for (int e = 0; e < 8; ++e) {
        int d = ch * 8 + e;
        *(__bf16*)(smem + VT_O + d * 208 + ((tc ^ xr) << 4) + tb) = v8[e];
      }
    }
  }
  __syncthreads();

  int ljv[6]; bool cok[6];
#pragma unroll
  for (int j = 0; j < 6; ++j) {
    int col = j * 16 + r16;
    ljv[j] = mod29(col);
    cok[j] = col < 87;
  }

  for (int m = wave; m < 6; m += 4) {
    f32x4 s[6] = {};
#pragma unroll
    for (int kk = 0; kk < 2; ++kk) {
      bf16x8 aq = *(const bf16x8*)(smem + QS_O + (m * 16 + r16) * 144 + kk * 64 + r4 * 16);
#pragma unroll
      for (int j = 0; j < 6; ++j) {
        bf16x8 kb = *(const bf16x8*)(smem + KS_O + (j * 16 + r16) * 144 + kk * 64 + r4 * 16);
        s[j] = __builtin_amdgcn_mfma_f32_16x16x32_bf16(aq, kb, s[j], 0, 0, 0);
      }
    }
#pragma unroll
    for (int rr = 0; rr < 4; ++rr) {
      int row = m * 16 + r4 * 4 + rr;
      bool rok = row < 87;
      int lr = mod29(row);
      float mxv = -1e30f;
#pragma unroll
      for (int j = 0; j < 6; ++j) {
        bool al = rok && cok[j] && (ljv[j] <= lr) && (ljv[j] + 21 >= lr);
        float sv = al ? s[j][rr] * 0.125f : -1e30f;
        s[j][rr] = sv;
        mxv = fmaxf(mxv, sv);
      }
      mxv = fmaxf(mxv, __shfl_xor(mxv, 1));
      mxv = fmaxf(mxv, __shfl_xor(mxv, 2));
      mxv = fmaxf(mxv, __shfl_xor(mxv, 4));
      mxv = fmaxf(mxv, __shfl_xor(mxv, 8));
      float sm = 0.f;
#pragma unroll
      for (int j = 0; j < 6; ++j) {
        float e = __expf(s[j][rr] - mxv);
        s[j][rr] = e;
        sm += e;
      }
      sm += __shfl_xor(sm, 1);
      sm += __shfl_xor(sm, 2);
      sm += __shfl_xor(sm, 4);
      sm += __shfl_xor(sm, 8);
      float inv = rok ? 1.f / sm : 0.f;
#pragma unroll
      for (int j = 0; j < 6; ++j)
        *(__hip_bfloat16*)(smem + PB_O + row * 208 + (j * 16 + r16) * 2) =
            __float2bfloat16(s[j][rr] * inv);
    }
  }
  __syncthreads();

  for (int p = 0; p < 6; ++p) {
    int pair = wave + p * 4;
    int mt = pair >> 2, nt = pair & 3;
    int d = nt * 16 + r16;
    int dx = (d >> 3) & 3;
    f32x4 acc = {0.f, 0.f, 0.f, 0.f};
#pragma unroll
    for (int kk = 0; kk < 3; ++kk) {
      bf16x8 a  = *(const bf16x8*)(smem + PB_O + (mt * 16 + r16) * 208 + kk * 64 + r4 * 16);
      bf16x8 bb = *(const bf16x8*)(smem + VT_O + d * 208 + (((kk * 4 + r4) ^ dx) << 4));
      acc = __builtin_amdgcn_mfma_f32_16x16x32_bf16(a, bb, acc, 0, 0, 0);
    }
    int t0 = mt * 16 + r4 * 4;
#pragma unroll
    for (int r = 0; r < 4; ++r)
      *(__bf16*)(smem + QS_O + (t0 + r) * 136 + d * 2) =
          __builtin_bit_cast(__bf16, __builtin_bit_cast(unsigned short, __float2bfloat16(acc[r])));
  }
  __syncthreads();

  for (int i = tid; i < 768; i += 256) {
    int row = i >> 3, ch = i & 7;
    if (row < 87) {
      bf16x8 vrow = *(const bf16x8*)(smem + QS_O + row * 136 + ch * 16);
      *(bf16x8*)((char*)y_ws + ((size_t)b * 87 + row) * 1024 + h * 128 + ch * 16) = vrow;
    }
  }
}

// ---------------- launch ----------------
extern "C" void kernel_launch(void* const* d_in, const int* in_sizes, int n_in,
                              void* d_out, int out_size, void* d_ws, size_t ws_size,
                              hipStream_t stream) {
  const float* x  = (const float*)d_in[0];
  const float* Wq = (const float*)d_in[1];
  const float* bq = (const float*)d_in[2];
  const float* Wk = (const float*)d_in[3];
  const float* bk = (const float*)d_in[4];
  const float* Wv = (const float*)d_in[5];
  const float* bv = (const float*)d_in[6];
  const float* Wp = (const float*)d_in[7];
  const float* bp = (const float*)d_in[8];
  float* out = (float*)d_out;

  char* ws = (char*)d_ws;
  size_t off = 0;
  __hip_bfloat16* xb    = (__hip_bfloat16*)(ws + off); off += (size_t)BT_ * 512 * 2;
  __hip_bfloat16* wqkv  = (__hip_bfloat16*)(ws + off); off += 1536 * 512 * 2;
  __hip_bfloat16* wp    = (__hip_bfloat16*)(ws + off); off += 512 * 512 * 2;
  float*          biasc = (float*)(ws + off);          off += 8192;
  __hip_bfloat16* q_ws  = (__hip_bfloat16*)(ws + off); off += (size_t)BH_ * 6144 * 2;
  __hip_bfloat16* k_ws  = (__hip_bfloat16*)(ws + off); off += (size_t)BH_ * 6144 * 2;
  __hip_bfloat16* v_ws  = (__hip_bfloat16*)(ws + off); off += (size_t)BH_ * 6144 * 2;
  __hip_bfloat16* yb = xb;  // alias: xb fully consumed by qkv before attn writes y

  if (ws_size < off) return;

  convert_x_kernel<<<2048, 256, 0, stream>>>(x, xb, BT_ * 512 / 4);
  convert_w_kernel<<<1024, 256, 0, stream>>>(Wq, Wk, Wv, Wp, bq, bk, bv, wqkv, wp, biasc);
  // qkv: 128x128 tiles -> 348 x 12 = 4176 blocks (div by 8)
  gemmr_kernel<0><<<4176, 256, 0, stream>>>(xb, wqkv, biasc, 12, q_ws, k_ws, v_ws);
  attn_kernel<<<BH_, 256, 0, stream>>>(q_ws, k_ws, v_ws, yb);
  // proj: 128x128 tiles -> 348 x 4 = 1392 blocks (div by 8)
  gemmr_kernel<1><<<1392, 256, 0, stream>>>(yb, wp, bp, 4, out, nullptr, nullptr);
}